// Round 5
// baseline (203393.982 us; speedup 1.0000x reference)
//
#include <hip/hip_runtime.h>

// problem dims
#define B_   64
#define T_   800
#define U_   64
#define N_   64
#define KMIX 10
#define H_   512
#define O_   121
#define C4_  2048   // 4*H

// grid layout: homogeneous-role blocks
#define NB_L0  64
#define NB_L1  64
#define NB_L2  64
#define NB_OUT 16
#define NB_ATT 4
#define NBLK  (NB_L0 + NB_L1 + NB_L2 + NB_OUT + NB_ATT)  // 212
#define NTHR  512
#define NITER (T_ + 3)  // pipeline: L0@i, ATT/L1@i-1, L2@i-2, OUT@i-3

struct Params {
  const float* strokes; const float* transcr;
  const float* W0; const float* b0;
  const float* bd;
  const float* W1; const float* b1;
  const float* W2; const float* b2;
  const float* bo;
  const float4* PR0; const float4* PW0w;
  const float4* PH1; const float4* PR1; const float4* PW1w;
  const float4* PH2; const float4* PR2; const float4* PW2w;
  const float4* PWo; const float4* PWd;
  float* h0r; float* h1r; float* h2r;   // rings [4][B][H] — cross-block, coherent access
  float* wr;                            // ring [4][B][N]  — cross-block, coherent access
  int*   bar;                           // [2*NITER] barrier counters
  float* outp; float* attp;
};

__device__ __forceinline__ float sigf(float x) { return 1.0f / (1.0f + expf(-x)); }

// quantize a double onto the fp32 grid INCLUDING subnormals, round-half-even.
__device__ __forceinline__ double f32q(double x) {
  double ax = fabs(x);
  if (ax >= 0x1p-126) return (double)(float)x;   // normal range: HW cast is exact RN
  return rint(x * 0x1p149) * 0x1p-149;           // subnormal grid in exact double arith
}

// Coherent (L1/L2-bypassing) 16B load for cross-XCD state.
// volatile double is a SCALAR type (no HIP_vector_type copy-ctor issue);
// two volatile 8B loads lower to global_load_dwordx2 with bypass flags.
__device__ __forceinline__ float4 vload4(const float4* p) {
  const volatile double* q = (const volatile double*)p;
  double d0 = q[0], d1 = q[1];
  union { double d; float f[2]; } u0, u1;
  u0.d = d0; u1.d = d1;
  return make_float4(u0.f[0], u0.f[1], u1.f[0], u1.f[1]);
}
__device__ __forceinline__ void vstoref(float* p, float v) {
  *(volatile float*)p = v;
}

// Fence-free grid barrier: __syncthreads() drains each wave's vmcnt (its
// volatile write-through stores are at the LLC once acked), then t0 does a
// relaxed agent-scope arrive+spin at the LLC. NO release/acquire fence =>
// NO buffer_wbl2 / buffer_inv => weights stay L2-resident across iterations.
__device__ __forceinline__ void gridbar(int* ctr, int tid) {
  __syncthreads();
  if (tid == 0) {
    atomicAdd(ctr, 1);
    while (__hip_atomic_load(ctr, __ATOMIC_RELAXED, __HIP_MEMORY_SCOPE_AGENT) < NBLK) {
      __builtin_amdgcn_s_sleep(1);
    }
  }
  __syncthreads();
}

// z-GEMV core: 4 gate columns (g*512+uj) share one X stream.
// W packed k-interleaved (plain loads — L2-hot); X = recurrent state (coherent).
__device__ __forceinline__ void dot4gv(const float* __restrict__ Xf,
                                       const float4* __restrict__ W,
                                       int k4, int uj, float acc[4]) {
  const float4* X = (const float4*)Xf;
  #pragma unroll 4
  for (int kk = 0; kk < k4; ++kk) {
    float4 xv = vload4(X + kk);
    #pragma unroll
    for (int g = 0; g < 4; ++g) {
      float4 wv = W[kk * C4_ + g * H_ + uj];
      acc[g] = fmaf(xv.x, wv.x, acc[g]);
      acc[g] = fmaf(xv.y, wv.y, acc[g]);
      acc[g] = fmaf(xv.z, wv.z, acc[g]);
      acc[g] = fmaf(xv.w, wv.w, acc[g]);
    }
  }
}

__device__ __forceinline__ float dot1v(const float4* __restrict__ X,
                                       const float4* __restrict__ W,
                                       int k4, int stride) {
  float a = 0.0f;
  #pragma unroll 4
  for (int kk = 0; kk < k4; ++kk) {
    float4 xv = vload4(X + kk);
    float4 wv = W[kk * stride];
    a = fmaf(xv.x, wv.x, a); a = fmaf(xv.y, wv.y, a);
    a = fmaf(xv.z, wv.z, a); a = fmaf(xv.w, wv.w, a);
  }
  return a;
}

// repack row-major (K x C, leading dim ld) into k-interleaved float4 layout
__global__ void pack_k(const float* __restrict__ src, float* __restrict__ dst,
                       int K, int C, int ld) {
  int idx = blockIdx.x * 256 + threadIdx.x;
  if (idx >= K * C) return;
  int k = idx / C, c = idx - k * C;
  dst[(size_t)(k >> 2) * C * 4 + (size_t)c * 4 + (k & 3)] = src[(size_t)k * ld + c];
}

__global__ __launch_bounds__(NTHR, 2)
void net_kernel(Params p) {
  const int q = blockIdx.x;
  const int t = threadIdx.x;

  __shared__ float  s_y[16][32];    // y = exp(h0@Wd+bd): alpha 0..9, beta 10..19
  __shared__ float  s_k2[16][10];   // kappa2 (this step)
  __shared__ float  s_kap[16][10];  // persistent kappa state (ATT blocks only)
  __shared__ double s_wf[16][66];   // wfull on the numpy-fp32 grid (held in double)

  // init persistent LDS kappa
  for (int z = t; z < 160; z += NTHR) ((float*)s_kap)[z] = 0.0f;
  __syncthreads();

  float creg = 0.0f;   // LSTM cell state: thread <-> (ub,uj) is static

  for (int i = 0; i < NITER; ++i) {
    float acc[4] = {0.f, 0.f, 0.f, 0.f};
    int uj = 0, ub = 0;
    bool act = false;

    // ---------------- phase A ----------------
    if (q < NB_L0) {                                  // layer0 z, t = i
      act = (i < T_);
      if (act) {
        uj = q * 8 + (t & 7); ub = t >> 3;
        const float* xs = &p.strokes[(ub * T_ + i) * 3];
        float x0 = xs[0], x1 = xs[1], x2 = xs[2];
        #pragma unroll
        for (int g = 0; g < 4; ++g) {
          int col = g * H_ + uj;
          acc[g] = p.b0[col] + x0 * p.W0[col] + x1 * p.W0[C4_ + col] + x2 * p.W0[2 * C4_ + col];
        }
        dot4gv(&p.h0r[(size_t)((((i - 1) & 3)) * B_ + ub) * H_], p.PR0, H_ / 4, uj, acc);
      }
    } else if (q < NB_L0 + NB_L1) {                   // layer1 z (minus w part), t = i-1
      act = (i >= 1 && i <= T_);
      if (act) {
        int tt = i - 1;
        uj = (q - NB_L0) * 8 + (t & 7); ub = t >> 3;
        const float* xs = &p.strokes[(ub * T_ + tt) * 3];
        float x0 = xs[0], x1 = xs[1], x2 = xs[2];
        #pragma unroll
        for (int g = 0; g < 4; ++g) {
          int col = g * H_ + uj;
          acc[g] = p.b1[col] + x0 * p.W1[576 * C4_ + col] + x1 * p.W1[577 * C4_ + col]
                             + x2 * p.W1[578 * C4_ + col];
        }
        dot4gv(&p.h0r[(size_t)((tt & 3) * B_ + ub) * H_], p.PH1, H_ / 4, uj, acc);
        dot4gv(&p.h1r[(size_t)(((i - 2) & 3) * B_ + ub) * H_], p.PR1, H_ / 4, uj, acc);
      }
    } else if (q < NB_L0 + NB_L1 + NB_L2) {           // layer2 z (complete), t = i-2
      act = (i >= 2 && i <= T_ + 1);
      if (act) {
        int tt = i - 2;
        uj = (q - NB_L0 - NB_L1) * 8 + (t & 7); ub = t >> 3;
        const float* xs = &p.strokes[(ub * T_ + tt) * 3];
        float x0 = xs[0], x1 = xs[1], x2 = xs[2];
        #pragma unroll
        for (int g = 0; g < 4; ++g) {
          int col = g * H_ + uj;
          acc[g] = p.b2[col] + x0 * p.W2[576 * C4_ + col] + x1 * p.W2[577 * C4_ + col]
                             + x2 * p.W2[578 * C4_ + col];
        }
        dot4gv(&p.h1r[(size_t)((tt & 3) * B_ + ub) * H_], p.PH2, H_ / 4, uj, acc);
        dot4gv(&p.wr[(size_t)((tt & 3) * B_ + ub) * N_], p.PW2w, N_ / 4, uj, acc);
        dot4gv(&p.h2r[(size_t)(((i - 3) & 3) * B_ + ub) * H_], p.PR2, H_ / 4, uj, acc);
      }
    } else if (q < NB_L0 + NB_L1 + NB_L2 + NB_OUT) {  // output row, t = i-3
      act = (i >= 3 && i <= T_ + 2);
      if (act) {
        int tt = i - 3;
        int qo = q - NB_L0 - NB_L1 - NB_L2;
        int o0 = (qo * O_) / NB_OUT, o1 = ((qo + 1) * O_) / NB_OUT;
        int ol = t & 7; ub = t >> 3;
        if (ol < o1 - o0) {
          int oo = o0 + ol;
          int sl = tt & 3;
          const float4* X0 = (const float4*)&p.h0r[(size_t)(sl * B_ + ub) * H_];
          const float4* X1 = (const float4*)&p.h1r[(size_t)(sl * B_ + ub) * H_];
          const float4* X2 = (const float4*)&p.h2r[(size_t)(sl * B_ + ub) * H_];
          float a = p.bo[oo];
          a += dot1v(X0, p.PWo + oo, 128, O_);
          a += dot1v(X1, p.PWo + (size_t)128 * O_ + oo, 128, O_);
          a += dot1v(X2, p.PWo + (size_t)256 * O_ + oo, 128, O_);
          p.outp[(size_t)(ub * T_ + tt) * O_ + oo] = a;  // clip is identity fwd
        }
      }
    } else {                                          // attention, t = i-1
      act = (i >= 1 && i <= T_);
      if (act) {
        int tt = i - 1;
        int qa = q - NB_L0 - NB_L1 - NB_L2 - NB_OUT;
        int lb = t >> 5, s = t & 31;
        ub = qa * 16 + lb;
        int sl = tt & 3;
        if (s < 30) {
          const float4* Xh = (const float4*)&p.h0r[(size_t)(sl * B_ + ub) * H_];
          float a = p.bd[s] + dot1v(Xh, p.PWd + s, 128, 30);
          float y = expf(a);
          s_y[lb][s] = y;
          if (s >= 20) {  // dk -> kappa update (persistent LDS state)
            float k2 = s_kap[lb][s - 20] + y;
            s_kap[lb][s - 20] = k2;
            s_k2[lb][s - 20] = k2;
          }
        }
        __syncthreads();
        // numpy-fp32 underflow-exact wfull (validated in R3: absmax 0.0156)
        for (int u = s; u < U_ + 1; u += 32) {
          double wf = 0.0;
          #pragma unroll
          for (int k = 0; k < KMIX; ++k) {
            float d32 = s_k2[lb][k] - (float)(u + 1);
            float sq  = d32 * d32;
            float m   = -(s_y[lb][10 + k] * sq);
            double e  = exp((double)m);
            double e32 = (e < 0x1p-126) ? 0.0 : (double)(float)e;
            wf += f32q((double)s_y[lb][k] * e32);
          }
          s_wf[lb][u] = wf;
        }
        __syncthreads();
        if (s == 0) {  // argmax over 65, first-max wins (strict >)
          int am = 0; double bv = s_wf[lb][0];
          for (int u = 1; u < U_ + 1; ++u) {
            double v = s_wf[lb][u];
            if (v > bv) { bv = v; am = u; }
          }
          p.attp[ub * T_ + tt] = (float)am;
        }
        for (int n = s; n < N_; n += 32) {  // w2 = wfull[:,:U] @ transcriptions[b]
          float a2 = 0.f;
          for (int u = 0; u < U_; ++u)
            a2 = fmaf((float)s_wf[lb][u], p.transcr[(size_t)(ub * U_ + u) * N_ + n], a2);
          vstoref(&p.wr[(size_t)(sl * B_ + ub) * N_ + n], a2);
        }
      }
    }

    gridbar(p.bar + 2 * i, t);

    // ---------------- phase B (w-dependent adds + LSTM pointwise) ----------------
    if (q < NB_L0) {
      if (act) {
        dot4gv(&p.wr[(size_t)(((i - 1) & 3) * B_ + ub) * N_], p.PW0w, N_ / 4, uj, acc);
        float cn = sigf(acc[1]) * creg + sigf(acc[0]) * tanhf(acc[2]);
        float hn = sigf(acc[3]) * tanhf(cn);
        creg = cn;
        vstoref(&p.h0r[(size_t)((i & 3) * B_ + ub) * H_ + uj], hn);
      }
    } else if (q < NB_L0 + NB_L1) {
      if (act) {
        int tt = i - 1;
        dot4gv(&p.wr[(size_t)((tt & 3) * B_ + ub) * N_], p.PW1w, N_ / 4, uj, acc);
        float cn = sigf(acc[1]) * creg + sigf(acc[0]) * tanhf(acc[2]);
        float hn = sigf(acc[3]) * tanhf(cn);
        creg = cn;
        vstoref(&p.h1r[(size_t)((tt & 3) * B_ + ub) * H_ + uj], hn);
      }
    } else if (q < NB_L0 + NB_L1 + NB_L2) {
      if (act) {
        int tt = i - 2;
        float cn = sigf(acc[1]) * creg + sigf(acc[0]) * tanhf(acc[2]);
        float hn = sigf(acc[3]) * tanhf(cn);
        creg = cn;
        vstoref(&p.h2r[(size_t)((tt & 3) * B_ + ub) * H_ + uj], hn);
      }
    }

    gridbar(p.bar + 2 * i + 1, t);
  }
}

extern "C" void kernel_launch(void* const* d_in, const int* in_sizes, int n_in,
                              void* d_out, int out_size, void* d_ws, size_t ws_size,
                              hipStream_t stream) {
  (void)in_sizes; (void)n_in; (void)out_size; (void)ws_size;
  const float* strokes = (const float*)d_in[0];
  const float* transcr = (const float*)d_in[1];
  const float* W0 = (const float*)d_in[2];
  const float* R0 = (const float*)d_in[3];
  const float* b0 = (const float*)d_in[4];
  const float* Wd = (const float*)d_in[5];
  const float* bd = (const float*)d_in[6];
  const float* W1 = (const float*)d_in[7];
  const float* R1 = (const float*)d_in[8];
  const float* b1 = (const float*)d_in[9];
  const float* W2 = (const float*)d_in[10];
  const float* R2 = (const float*)d_in[11];
  const float* b2 = (const float*)d_in[12];
  const float* Wo = (const float*)d_in[13];
  const float* bo = (const float*)d_in[14];

  float* ws = (float*)d_ws;
  size_t off = 0;
  float* h0r = ws + off; off += (size_t)4 * B_ * H_;
  float* h1r = ws + off; off += (size_t)4 * B_ * H_;
  float* h2r = ws + off; off += (size_t)4 * B_ * H_;
  float* wr  = ws + off; off += (size_t)4 * B_ * N_;
  int*   bar = (int*)(ws + off); off += (size_t)2 * NITER;
  size_t stateFloats = off;
  float* PR0  = ws + off; off += (size_t)512 * 2048;
  float* PW0w = ws + off; off += (size_t)64 * 2048;
  float* PH1  = ws + off; off += (size_t)512 * 2048;
  float* PR1  = ws + off; off += (size_t)512 * 2048;
  float* PW1w = ws + off; off += (size_t)64 * 2048;
  float* PH2  = ws + off; off += (size_t)512 * 2048;
  float* PR2  = ws + off; off += (size_t)512 * 2048;
  float* PW2w = ws + off; off += (size_t)64 * 2048;
  float* PWo  = ws + off; off += (size_t)1536 * 121;
  float* PWd  = ws + off; off += (size_t)512 * 30;

  // zero recurrent state + barrier counters (ws is poisoned 0xAA before every call)
  (void)hipMemsetAsync(d_ws, 0, stateFloats * sizeof(float), stream);

  auto packl = [&](const float* src, float* dst, int K, int C, int ld) {
    int n = K * C;
    pack_k<<<dim3((n + 255) / 256), dim3(256), 0, stream>>>(src, dst, K, C, ld);
  };
  packl(R0, PR0, 512, 2048, 2048);
  packl(W0 + 3 * 2048, PW0w, 64, 2048, 2048);
  packl(W1, PH1, 512, 2048, 2048);
  packl(R1, PR1, 512, 2048, 2048);
  packl(W1 + 512 * 2048, PW1w, 64, 2048, 2048);
  packl(W2, PH2, 512, 2048, 2048);
  packl(R2, PR2, 512, 2048, 2048);
  packl(W2 + 512 * 2048, PW2w, 64, 2048, 2048);
  packl(Wo, PWo, 1536, 121, 121);
  packl(Wd, PWd, 512, 30, 30);

  Params p;
  p.strokes = strokes; p.transcr = transcr;
  p.W0 = W0; p.b0 = b0; p.bd = bd;
  p.W1 = W1; p.b1 = b1; p.W2 = W2; p.b2 = b2; p.bo = bo;
  p.PR0 = (const float4*)PR0; p.PW0w = (const float4*)PW0w;
  p.PH1 = (const float4*)PH1; p.PR1 = (const float4*)PR1; p.PW1w = (const float4*)PW1w;
  p.PH2 = (const float4*)PH2; p.PR2 = (const float4*)PR2; p.PW2w = (const float4*)PW2w;
  p.PWo = (const float4*)PWo; p.PWd = (const float4*)PWd;
  p.h0r = h0r; p.h1r = h1r; p.h2r = h2r;
  p.wr = wr; p.bar = bar;
  p.outp = (float*)d_out;
  p.attp = (float*)d_out + (size_t)B_ * T_ * O_;

  void* args[] = { (void*)&p };
  (void)hipLaunchCooperativeKernel((const void*)net_kernel, dim3(NBLK), dim3(NTHR),
                                   args, 0, stream);
}

// Round 6
// 109754.956 us; speedup vs baseline: 1.8532x; 1.8532x over previous
//
#include <hip/hip_runtime.h>

// problem dims
#define B_   64
#define T_   800
#define U_   64
#define N_   64
#define KMIX 10
#define H_   512
#define O_   121
#define C4_  2048   // 4*H

// grid layout: (batch-group x column-group) blocks, colg = blockIdx%8 -> XCD
#define NB_L0  64   // 8 bq x 8 colg
#define NB_L1  64
#define NB_L2  64
#define NB_OUT 8    // 1 per bq
#define NB_ATT 4    // 16 b each
#define NBLK  (NB_L0 + NB_L1 + NB_L2 + NB_OUT + NB_ATT)  // 204
#define NTHR  512
#define RING  8
#define FS    8     // ints per flag slot (32B spacing)

struct Params {
  const float* strokes; const float* transcr;
  const float* W0; const float* b0;
  const float* bd;
  const float* W1; const float* b1;
  const float* W2; const float* b2;
  const float* bo;
  const float4* PR0; const float4* PW0w;
  const float4* PH1; const float4* PR1; const float4* PW1w;
  const float4* PH2; const float4* PR2; const float4* PW2w;
  const float4* PWo; const float4* PWd;
  float* h0r; float* h1r; float* h2r;   // rings [RING][B][H], coherent access
  float* wr;                            // ring [RING][B][N]
  int *h0f, *h1f, *h2f, *wfl, *outf;    // flags [T][8 bq][FS]
  float* outp; float* attp;
};

__device__ __forceinline__ float sigf(float x) { return 1.0f / (1.0f + expf(-x)); }

// quantize a double onto the fp32 grid INCLUDING subnormals, round-half-even.
__device__ __forceinline__ double f32q(double x) {
  double ax = fabs(x);
  if (ax >= 0x1p-126) return (double)(float)x;
  return rint(x * 0x1p149) * 0x1p-149;
}

// ---- coherent (LLC-point) but UNORDERED accesses: relaxed agent atomics ----
// (R5 lesson: volatile = compiler-ordered -> one waitcnt per load -> serialized.
//  relaxed atomics hit the same coherence point but pipeline freely.)
__device__ __forceinline__ float4 cload4(const float4* p) {
  const double* q = (const double*)p;
  double d0 = __hip_atomic_load(q,     __ATOMIC_RELAXED, __HIP_MEMORY_SCOPE_AGENT);
  double d1 = __hip_atomic_load(q + 1, __ATOMIC_RELAXED, __HIP_MEMORY_SCOPE_AGENT);
  union { double d; float f[2]; } u0, u1;
  u0.d = d0; u1.d = d1;
  return make_float4(u0.f[0], u0.f[1], u1.f[0], u1.f[1]);
}
__device__ __forceinline__ void cstoref(float* p, float v) {
  __hip_atomic_store(p, v, __ATOMIC_RELAXED, __HIP_MEMORY_SCOPE_AGENT);
}

// ---- bq-local flags: <=8 RMWs per line (vs 212-way barrier contention) ----
__device__ __forceinline__ int* FP(int* arr, int tt, int bq) {
  return arr + ((size_t)tt * 8 + bq) * FS;
}
__device__ __forceinline__ void waitflag(const int* f, int target) {
  while (__hip_atomic_load(f, __ATOMIC_RELAXED, __HIP_MEMORY_SCOPE_AGENT) < target)
    __builtin_amdgcn_s_sleep(2);
}
__device__ __forceinline__ void postflag(int* f) {
  __hip_atomic_fetch_add(f, 1, __ATOMIC_RELAXED, __HIP_MEMORY_SCOPE_AGENT);
}

// z-GEMV core: 4 gate columns share one X stream (wave-uniform broadcast).
__device__ __forceinline__ void dot4gc(const float* Xrow,
                                       const float4* __restrict__ W,
                                       int k4, int col, float acc[4]) {
  const float4* X = (const float4*)Xrow;
  #pragma unroll 2
  for (int kk = 0; kk < k4; ++kk) {
    float4 xv = cload4(X + kk);
    #pragma unroll
    for (int g = 0; g < 4; ++g) {
      float4 wv = W[kk * C4_ + g * H_ + col];
      acc[g] = fmaf(xv.x, wv.x, acc[g]);
      acc[g] = fmaf(xv.y, wv.y, acc[g]);
      acc[g] = fmaf(xv.z, wv.z, acc[g]);
      acc[g] = fmaf(xv.w, wv.w, acc[g]);
    }
  }
}

__device__ __forceinline__ float dot1c(const float4* X,
                                       const float4* __restrict__ W,
                                       int k4, int stride) {
  float a = 0.0f;
  #pragma unroll 4
  for (int kk = 0; kk < k4; ++kk) {
    float4 xv = cload4(X + kk);
    float4 wv = W[kk * stride];
    a = fmaf(xv.x, wv.x, a); a = fmaf(xv.y, wv.y, a);
    a = fmaf(xv.z, wv.z, a); a = fmaf(xv.w, wv.w, a);
  }
  return a;
}

// repack row-major (K x C, leading dim ld) into k-interleaved float4 layout
__global__ void pack_k(const float* __restrict__ src, float* __restrict__ dst,
                       int K, int C, int ld) {
  int idx = blockIdx.x * 256 + threadIdx.x;
  if (idx >= K * C) return;
  int k = idx / C, c = idx - k * C;
  dst[(size_t)(k >> 2) * C * 4 + (size_t)c * 4 + (k & 3)] = src[(size_t)k * ld + c];
}

__global__ __launch_bounds__(NTHR, 2)
void net_kernel(Params p) {
  const int q = blockIdx.x;
  const int t = threadIdx.x;

  if (q < NB_L0) {                                   // ---- layer 0 ----
    const int bq = q >> 3, colg = q & 7;
    const int bl = t >> 6, cl = t & 63;
    const int b = bq * 8 + bl, col = colg * 64 + cl;
    float creg = 0.0f;
    for (int i = 0; i < T_; ++i) {
      if (t == 0) {
        if (i >= 1) waitflag(FP(p.h0f, i - 1, bq), 8);
        if (i >= 8) waitflag(FP(p.outf, i - 8, bq), 1);
      }
      __syncthreads();
      float acc[4];
      const float* xs = &p.strokes[(b * T_ + i) * 3];
      float x0 = xs[0], x1 = xs[1], x2 = xs[2];
      #pragma unroll
      for (int g = 0; g < 4; ++g) {
        int cg = g * H_ + col;
        acc[g] = p.b0[cg] + x0 * p.W0[cg] + x1 * p.W0[C4_ + cg] + x2 * p.W0[2 * C4_ + cg];
      }
      dot4gc(&p.h0r[(size_t)(((i - 1) & (RING - 1)) * B_ + b) * H_], p.PR0, H_ / 4, col, acc);
      if (t == 0 && i >= 1) waitflag(FP(p.wfl, i - 1, bq), 1);
      __syncthreads();
      dot4gc(&p.wr[(size_t)(((i - 1) & (RING - 1)) * B_ + b) * N_], p.PW0w, N_ / 4, col, acc);
      float cn = sigf(acc[1]) * creg + sigf(acc[0]) * tanhf(acc[2]);
      float hn = sigf(acc[3]) * tanhf(cn);
      creg = cn;
      cstoref(&p.h0r[(size_t)((i & (RING - 1)) * B_ + b) * H_ + col], hn);
      __syncthreads();
      if (t == 0) postflag(FP(p.h0f, i, bq));
    }
  } else if (q < NB_L0 + NB_L1) {                    // ---- layer 1 ----
    const int qq = q - NB_L0;
    const int bq = qq >> 3, colg = qq & 7;
    const int bl = t >> 6, cl = t & 63;
    const int b = bq * 8 + bl, col = colg * 64 + cl;
    float creg = 0.0f;
    for (int i = 1; i <= T_; ++i) {
      const int tt = i - 1;
      if (t == 0) {
        waitflag(FP(p.h0f, tt, bq), 8);
        if (tt >= 1) waitflag(FP(p.h1f, tt - 1, bq), 8);
        if (i >= 8) waitflag(FP(p.outf, i - 8, bq), 1);
      }
      __syncthreads();
      float acc[4];
      const float* xs = &p.strokes[(b * T_ + tt) * 3];
      float x0 = xs[0], x1 = xs[1], x2 = xs[2];
      #pragma unroll
      for (int g = 0; g < 4; ++g) {
        int cg = g * H_ + col;
        acc[g] = p.b1[cg] + x0 * p.W1[576 * C4_ + cg] + x1 * p.W1[577 * C4_ + cg]
                          + x2 * p.W1[578 * C4_ + cg];
      }
      dot4gc(&p.h0r[(size_t)((tt & (RING - 1)) * B_ + b) * H_], p.PH1, H_ / 4, col, acc);
      dot4gc(&p.h1r[(size_t)(((tt - 1) & (RING - 1)) * B_ + b) * H_], p.PR1, H_ / 4, col, acc);
      if (t == 0) waitflag(FP(p.wfl, tt, bq), 1);
      __syncthreads();
      dot4gc(&p.wr[(size_t)((tt & (RING - 1)) * B_ + b) * N_], p.PW1w, N_ / 4, col, acc);
      float cn = sigf(acc[1]) * creg + sigf(acc[0]) * tanhf(acc[2]);
      float hn = sigf(acc[3]) * tanhf(cn);
      creg = cn;
      cstoref(&p.h1r[(size_t)((tt & (RING - 1)) * B_ + b) * H_ + col], hn);
      __syncthreads();
      if (t == 0) postflag(FP(p.h1f, tt, bq));
    }
  } else if (q < NB_L0 + NB_L1 + NB_L2) {            // ---- layer 2 ----
    const int qq = q - NB_L0 - NB_L1;
    const int bq = qq >> 3, colg = qq & 7;
    const int bl = t >> 6, cl = t & 63;
    const int b = bq * 8 + bl, col = colg * 64 + cl;
    float creg = 0.0f;
    for (int i = 2; i <= T_ + 1; ++i) {
      const int tt = i - 2;
      if (t == 0) {
        waitflag(FP(p.h1f, tt, bq), 8);
        waitflag(FP(p.wfl, tt, bq), 1);
        if (tt >= 1) waitflag(FP(p.h2f, tt - 1, bq), 8);
        if (i >= 8) waitflag(FP(p.outf, i - 8, bq), 1);
      }
      __syncthreads();
      float acc[4];
      const float* xs = &p.strokes[(b * T_ + tt) * 3];
      float x0 = xs[0], x1 = xs[1], x2 = xs[2];
      #pragma unroll
      for (int g = 0; g < 4; ++g) {
        int cg = g * H_ + col;
        acc[g] = p.b2[cg] + x0 * p.W2[576 * C4_ + cg] + x1 * p.W2[577 * C4_ + cg]
                          + x2 * p.W2[578 * C4_ + cg];
      }
      dot4gc(&p.h1r[(size_t)((tt & (RING - 1)) * B_ + b) * H_], p.PH2, H_ / 4, col, acc);
      dot4gc(&p.wr[(size_t)((tt & (RING - 1)) * B_ + b) * N_], p.PW2w, N_ / 4, col, acc);
      dot4gc(&p.h2r[(size_t)(((tt - 1) & (RING - 1)) * B_ + b) * H_], p.PR2, H_ / 4, col, acc);
      float cn = sigf(acc[1]) * creg + sigf(acc[0]) * tanhf(acc[2]);
      float hn = sigf(acc[3]) * tanhf(cn);
      creg = cn;
      cstoref(&p.h2r[(size_t)((tt & (RING - 1)) * B_ + b) * H_ + col], hn);
      __syncthreads();
      if (t == 0) postflag(FP(p.h2f, tt, bq));
    }
  } else if (q < NB_L0 + NB_L1 + NB_L2 + NB_OUT) {   // ---- output head ----
    const int bq = q - NB_L0 - NB_L1 - NB_L2;
    const int bl = t >> 6, ol = t & 63;
    const int b = bq * 8 + bl;
    const int oo1 = ol;
    const bool v2 = (ol < O_ - 64);
    const int oo2 = v2 ? (ol + 64) : 0;
    for (int i = 3; i <= T_ + 2; ++i) {
      const int tt = i - 3;
      if (t == 0) {
        waitflag(FP(p.h0f, tt, bq), 8);
        waitflag(FP(p.h1f, tt, bq), 8);
        waitflag(FP(p.h2f, tt, bq), 8);
      }
      __syncthreads();
      const int sl = tt & (RING - 1);
      const float4* X0 = (const float4*)&p.h0r[(size_t)(sl * B_ + b) * H_];
      const float4* X1 = (const float4*)&p.h1r[(size_t)(sl * B_ + b) * H_];
      const float4* X2 = (const float4*)&p.h2r[(size_t)(sl * B_ + b) * H_];
      float a1 = p.bo[oo1];
      a1 += dot1c(X0, p.PWo + oo1, 128, O_);
      a1 += dot1c(X1, p.PWo + (size_t)128 * O_ + oo1, 128, O_);
      a1 += dot1c(X2, p.PWo + (size_t)256 * O_ + oo1, 128, O_);
      float a2 = p.bo[oo2];
      a2 += dot1c(X0, p.PWo + oo2, 128, O_);
      a2 += dot1c(X1, p.PWo + (size_t)128 * O_ + oo2, 128, O_);
      a2 += dot1c(X2, p.PWo + (size_t)256 * O_ + oo2, 128, O_);
      __builtin_nontemporal_store(a1, &p.outp[(size_t)(b * T_ + tt) * O_ + oo1]);
      if (v2) __builtin_nontemporal_store(a2, &p.outp[(size_t)(b * T_ + tt) * O_ + oo2]);
      __syncthreads();
      if (t == 0) postflag(FP(p.outf, tt, bq));
    }
  } else {                                           // ---- attention ----
    const int qa = q - NB_L0 - NB_L1 - NB_L2 - NB_OUT;
    const int lb = t >> 5, s = t & 31;
    const int ub = qa * 16 + lb;
    __shared__ float  s_y[16][32];
    __shared__ float  s_k2[16][10];
    __shared__ float  s_kap[16][10];
    __shared__ double s_wf[16][66];
    for (int z = t; z < 160; z += NTHR) ((float*)s_kap)[z] = 0.0f;
    __syncthreads();
    for (int i = 1; i <= T_; ++i) {
      const int tt = i - 1;
      if (t == 0) {
        waitflag(FP(p.h0f, tt, 2 * qa), 8);
        waitflag(FP(p.h0f, tt, 2 * qa + 1), 8);
      }
      __syncthreads();
      const int sl = tt & (RING - 1);
      if (s < 30) {
        const float4* Xh = (const float4*)&p.h0r[(size_t)(sl * B_ + ub) * H_];
        float a = p.bd[s] + dot1c(Xh, p.PWd + s, 128, 30);
        float y = expf(a);
        s_y[lb][s] = y;
        if (s >= 20) {
          float k2 = s_kap[lb][s - 20] + y;
          s_kap[lb][s - 20] = k2;
          s_k2[lb][s - 20] = k2;
        }
      }
      __syncthreads();
      // numpy-fp32 underflow-exact wfull (validated R3: absmax 0.0156)
      for (int u = s; u < U_ + 1; u += 32) {
        double wf = 0.0;
        #pragma unroll
        for (int k = 0; k < KMIX; ++k) {
          float d32 = s_k2[lb][k] - (float)(u + 1);
          float sq  = d32 * d32;
          float m   = -(s_y[lb][10 + k] * sq);
          double e  = exp((double)m);
          double e32 = (e < 0x1p-126) ? 0.0 : (double)(float)e;
          wf += f32q((double)s_y[lb][k] * e32);
        }
        s_wf[lb][u] = wf;
      }
      __syncthreads();
      if (s == 0) {
        int am = 0; double bv = s_wf[lb][0];
        for (int u = 1; u < U_ + 1; ++u) {
          double v = s_wf[lb][u];
          if (v > bv) { bv = v; am = u; }
        }
        __builtin_nontemporal_store((float)am, &p.attp[ub * T_ + tt]);
      }
      for (int n = s; n < N_; n += 32) {
        float a2 = 0.f;
        for (int u = 0; u < U_; ++u)
          a2 = fmaf((float)s_wf[lb][u], p.transcr[(size_t)(ub * U_ + u) * N_ + n], a2);
        cstoref(&p.wr[(size_t)(sl * B_ + ub) * N_ + n], a2);
      }
      __syncthreads();
      if (t == 0) {
        postflag(FP(p.wfl, tt, 2 * qa));
        postflag(FP(p.wfl, tt, 2 * qa + 1));
      }
    }
  }
}

extern "C" void kernel_launch(void* const* d_in, const int* in_sizes, int n_in,
                              void* d_out, int out_size, void* d_ws, size_t ws_size,
                              hipStream_t stream) {
  (void)in_sizes; (void)n_in; (void)out_size; (void)ws_size;
  const float* strokes = (const float*)d_in[0];
  const float* transcr = (const float*)d_in[1];
  const float* W0 = (const float*)d_in[2];
  const float* R0 = (const float*)d_in[3];
  const float* b0 = (const float*)d_in[4];
  const float* Wd = (const float*)d_in[5];
  const float* bd = (const float*)d_in[6];
  const float* W1 = (const float*)d_in[7];
  const float* R1 = (const float*)d_in[8];
  const float* b1 = (const float*)d_in[9];
  const float* W2 = (const float*)d_in[10];
  const float* R2 = (const float*)d_in[11];
  const float* b2 = (const float*)d_in[12];
  const float* Wo = (const float*)d_in[13];
  const float* bo = (const float*)d_in[14];

  float* ws = (float*)d_ws;
  size_t off = 0;
  float* h0r = ws + off; off += (size_t)RING * B_ * H_;
  float* h1r = ws + off; off += (size_t)RING * B_ * H_;
  float* h2r = ws + off; off += (size_t)RING * B_ * H_;
  float* wr  = ws + off; off += (size_t)RING * B_ * N_;
  const size_t FLAGN = (size_t)T_ * 8 * FS;
  int* h0f  = (int*)(ws + off); off += FLAGN;
  int* h1f  = (int*)(ws + off); off += FLAGN;
  int* h2f  = (int*)(ws + off); off += FLAGN;
  int* wfl  = (int*)(ws + off); off += FLAGN;
  int* outf = (int*)(ws + off); off += FLAGN;
  size_t stateFloats = off;
  float* PR0  = ws + off; off += (size_t)512 * 2048;
  float* PW0w = ws + off; off += (size_t)64 * 2048;
  float* PH1  = ws + off; off += (size_t)512 * 2048;
  float* PR1  = ws + off; off += (size_t)512 * 2048;
  float* PW1w = ws + off; off += (size_t)64 * 2048;
  float* PH2  = ws + off; off += (size_t)512 * 2048;
  float* PR2  = ws + off; off += (size_t)512 * 2048;
  float* PW2w = ws + off; off += (size_t)64 * 2048;
  float* PWo  = ws + off; off += (size_t)1536 * 121;
  float* PWd  = ws + off; off += (size_t)512 * 30;

  // zero rings + flags (ws is poisoned 0xAA before every call)
  (void)hipMemsetAsync(d_ws, 0, stateFloats * sizeof(float), stream);

  auto packl = [&](const float* src, float* dst, int K, int C, int ld) {
    int n = K * C;
    pack_k<<<dim3((n + 255) / 256), dim3(256), 0, stream>>>(src, dst, K, C, ld);
  };
  packl(R0, PR0, 512, 2048, 2048);
  packl(W0 + 3 * 2048, PW0w, 64, 2048, 2048);
  packl(W1, PH1, 512, 2048, 2048);
  packl(R1, PR1, 512, 2048, 2048);
  packl(W1 + 512 * 2048, PW1w, 64, 2048, 2048);
  packl(W2, PH2, 512, 2048, 2048);
  packl(R2, PR2, 512, 2048, 2048);
  packl(W2 + 512 * 2048, PW2w, 64, 2048, 2048);
  packl(Wo, PWo, 1536, 121, 121);
  packl(Wd, PWd, 512, 30, 30);

  Params p;
  p.strokes = strokes; p.transcr = transcr;
  p.W0 = W0; p.b0 = b0; p.bd = bd;
  p.W1 = W1; p.b1 = b1; p.W2 = W2; p.b2 = b2; p.bo = bo;
  p.PR0 = (const float4*)PR0; p.PW0w = (const float4*)PW0w;
  p.PH1 = (const float4*)PH1; p.PR1 = (const float4*)PR1; p.PW1w = (const float4*)PW1w;
  p.PH2 = (const float4*)PH2; p.PR2 = (const float4*)PR2; p.PW2w = (const float4*)PW2w;
  p.PWo = (const float4*)PWo; p.PWd = (const float4*)PWd;
  p.h0r = h0r; p.h1r = h1r; p.h2r = h2r; p.wr = wr;
  p.h0f = h0f; p.h1f = h1f; p.h2f = h2f; p.wfl = wfl; p.outf = outf;
  p.outp = (float*)d_out;
  p.attp = (float*)d_out + (size_t)B_ * T_ * O_;

  void* args[] = { (void*)&p };
  (void)hipLaunchCooperativeKernel((const void*)net_kernel, dim3(NBLK), dim3(NTHR),
                                   args, 0, stream);
}

// Round 7
// 52034.082 us; speedup vs baseline: 3.9089x; 2.1093x over previous
//
#include <hip/hip_runtime.h>

// problem dims
#define B_   64
#define T_   800
#define U_   64
#define N_   64
#define KMIX 10
#define H_   512
#define O_   121
#define C4_  2048   // 4*H

// grid layout: (batch-group x column-group) blocks, colg -> XCD slice
#define NB_L0  64   // 8 bq x 8 colg
#define NB_L1  64
#define NB_L2  64
#define NB_OUT 8    // 1 per bq
#define NB_ATT 4    // 16 b each
#define NBLK  (NB_L0 + NB_L1 + NB_L2 + NB_OUT + NB_ATT)  // 204
#define NTHR  512
#define RING  8
#define RB    (RING - 1)
#define FS    8     // ints per flag slot (32B spacing)

#define AL(pp) __hip_atomic_load((pp), __ATOMIC_RELAXED, __HIP_MEMORY_SCOPE_AGENT)

struct Params {
  const float* strokes; const float* transcr;
  const float* W0; const float* b0;
  const float* bd;
  const float* W1; const float* b1;
  const float* W2; const float* b2;
  const float* bo;
  const float4* PR0; const float4* PW0w;
  const float4* PH1; const float4* PR1; const float4* PW1w;
  const float4* PH2; const float4* PR2; const float4* PW2w;
  const float4* PWo; const float4* PWd;
  float* h0r; float* h1r; float* h2r;   // rings [RING][B][H], coherent access
  float* wr;                            // ring [RING][B][N]
  int *h0f, *h1f, *h2f, *wfl, *outf;    // flags [T][8 bq][FS]
  float* outp; float* attp;
};

__device__ __forceinline__ float sigf(float x) { return 1.0f / (1.0f + expf(-x)); }

// quantize a double onto the fp32 grid INCLUDING subnormals, round-half-even.
__device__ __forceinline__ double f32q(double x) {
  double ax = fabs(x);
  if (ax >= 0x1p-126) return (double)(float)x;
  return rint(x * 0x1p149) * 0x1p-149;
}

__device__ __forceinline__ void cstoref(float* p, float v) {
  __hip_atomic_store(p, v, __ATOMIC_RELAXED, __HIP_MEMORY_SCOPE_AGENT);
}

// ---- bq-local flags ----
__device__ __forceinline__ int* FP(int* arr, int tt, int bq) {
  return arr + ((size_t)tt * 8 + bq) * FS;
}
__device__ __forceinline__ void waitflag(const int* f, int target) {
  while (__hip_atomic_load(f, __ATOMIC_RELAXED, __HIP_MEMORY_SCOPE_AGENT) < target)
    __builtin_amdgcn_s_sleep(1);
}
__device__ __forceinline__ void postflag(int* f) {
  __hip_atomic_fetch_add(f, 1, __ATOMIC_RELAXED, __HIP_MEMORY_SCOPE_AGENT);
}

// batched coherent stage: 4096 floats (one 8-row x 512 tile) -> LDS.
// All atomic loads issue back-to-back (no uses between) => ONE LLC round trip.
__device__ __forceinline__ void stage4k(float* dstL, const float* src, int t) {
  const double* s = (const double*)src;
  double v0 = AL(s + t), v1 = AL(s + 512 + t), v2 = AL(s + 1024 + t), v3 = AL(s + 1536 + t);
  double* d = (double*)dstL;
  d[t] = v0; d[512 + t] = v1; d[1024 + t] = v2; d[1536 + t] = v3;
}
// two tiles fused (one round trip for both)
__device__ __forceinline__ void stage4k2(float* d1, const float* s1,
                                         float* d2, const float* s2, int t) {
  const double* a = (const double*)s1;
  const double* b = (const double*)s2;
  double a0 = AL(a + t), a1 = AL(a + 512 + t), a2 = AL(a + 1024 + t), a3 = AL(a + 1536 + t);
  double b0 = AL(b + t), b1 = AL(b + 512 + t), b2 = AL(b + 1024 + t), b3 = AL(b + 1536 + t);
  double* dA = (double*)d1; dA[t] = a0; dA[512 + t] = a1; dA[1024 + t] = a2; dA[1536 + t] = a3;
  double* dB = (double*)d2; dB[t] = b0; dB[512 + t] = b1; dB[1024 + t] = b2; dB[1536 + t] = b3;
}
// 512-float stage (w ring row-group)
__device__ __forceinline__ void stage512(float* dstL, const float* src, int t) {
  if (t < 256) {
    double v = AL((const double*)src + t);
    ((double*)dstL)[t] = v;
  }
}

// z-GEMV core: X from LDS (wave-uniform broadcast), W plain loads (L2-hot).
__device__ __forceinline__ void dot4gl(const float* Xl,
                                       const float4* __restrict__ W,
                                       int k4, int col, float acc[4]) {
  const float4* X = (const float4*)Xl;
  #pragma unroll 2
  for (int kk = 0; kk < k4; ++kk) {
    float4 xv = X[kk];
    #pragma unroll
    for (int g = 0; g < 4; ++g) {
      float4 wv = W[kk * C4_ + g * H_ + col];
      acc[g] = fmaf(xv.x, wv.x, acc[g]);
      acc[g] = fmaf(xv.y, wv.y, acc[g]);
      acc[g] = fmaf(xv.z, wv.z, acc[g]);
      acc[g] = fmaf(xv.w, wv.w, acc[g]);
    }
  }
}

__device__ __forceinline__ float dot1l(const float* Xl,
                                       const float4* __restrict__ W,
                                       int k4, int stride) {
  const float4* X = (const float4*)Xl;
  float a = 0.0f;
  #pragma unroll 4
  for (int kk = 0; kk < k4; ++kk) {
    float4 xv = X[kk];
    float4 wv = W[kk * stride];
    a = fmaf(xv.x, wv.x, a); a = fmaf(xv.y, wv.y, a);
    a = fmaf(xv.z, wv.z, a); a = fmaf(xv.w, wv.w, a);
  }
  return a;
}

// repack row-major (K x C, leading dim ld) into k-interleaved float4 layout
__global__ void pack_k(const float* __restrict__ src, float* __restrict__ dst,
                       int K, int C, int ld) {
  int idx = blockIdx.x * 256 + threadIdx.x;
  if (idx >= K * C) return;
  int k = idx / C, c = idx - k * C;
  dst[(size_t)(k >> 2) * C * 4 + (size_t)c * 4 + (k & 3)] = src[(size_t)k * ld + c];
}

__global__ __launch_bounds__(NTHR, 2)
void net_kernel(Params p) {
  const int q = blockIdx.x;
  const int t = threadIdx.x;

  __shared__ float  s_buf[12288];   // staged X tiles (role-dependent layout)
  __shared__ float  s_y[16][32];
  __shared__ float  s_k2[16][10];
  __shared__ float  s_kap[16][10];
  __shared__ double s_wf[16][66];

  if (q < NB_L0) {                                   // ---- layer 0 ----
    const int bq = q >> 3, colg = q & 7;
    const int bl = t >> 6, cl = t & 63;
    const int b = bq * 8 + bl, col = colg * 64 + cl;
    float* sh = s_buf;            // h0(i-1): 8 x 512
    float* sw = s_buf + 4096;     // w(i-1):  8 x 64
    float creg = 0.0f;
    for (int i = 0; i < T_; ++i) {
      if (t == 0) {
        if (i >= 1) waitflag(FP(p.h0f, i - 1, bq), 8);
        if (i >= 8) waitflag(FP(p.outf, i - 8, bq), 1);
      }
      __syncthreads();
      const int slp = (i - 1) & RB;
      stage4k(sh, &p.h0r[((size_t)slp * B_ + bq * 8) * H_], t);
      float acc[4];
      const float* xs = &p.strokes[(b * T_ + i) * 3];
      float x0 = xs[0], x1 = xs[1], x2 = xs[2];
      #pragma unroll
      for (int g = 0; g < 4; ++g) {
        int cg = g * H_ + col;
        acc[g] = p.b0[cg] + x0 * p.W0[cg] + x1 * p.W0[C4_ + cg] + x2 * p.W0[2 * C4_ + cg];
      }
      __syncthreads();
      dot4gl(sh + bl * H_, p.PR0, H_ / 4, col, acc);
      if (t == 0 && i >= 1) waitflag(FP(p.wfl, i - 1, bq), 1);
      __syncthreads();
      stage512(sw, &p.wr[((size_t)slp * B_ + bq * 8) * N_], t);
      __syncthreads();
      dot4gl(sw + bl * N_, p.PW0w, N_ / 4, col, acc);
      float cn = sigf(acc[1]) * creg + sigf(acc[0]) * tanhf(acc[2]);
      float hn = sigf(acc[3]) * tanhf(cn);
      creg = cn;
      cstoref(&p.h0r[((size_t)(i & RB) * B_ + b) * H_ + col], hn);
      __syncthreads();
      if (t == 0) postflag(FP(p.h0f, i, bq));
    }
  } else if (q < NB_L0 + NB_L1) {                    // ---- layer 1 ----
    const int qq = q - NB_L0;
    const int bq = qq >> 3, colg = qq & 7;
    const int bl = t >> 6, cl = t & 63;
    const int b = bq * 8 + bl, col = colg * 64 + cl;
    float* sh0 = s_buf;           // h0(tt)
    float* sh1 = s_buf + 4096;    // h1(tt-1)
    float* sw  = s_buf + 8192;    // w(tt)
    float creg = 0.0f;
    for (int tt = 0; tt < T_; ++tt) {
      if (t == 0) {
        waitflag(FP(p.h0f, tt, bq), 8);
        if (tt >= 1) waitflag(FP(p.h1f, tt - 1, bq), 8);
        if (tt >= 7) waitflag(FP(p.outf, tt - 7, bq), 1);
      }
      __syncthreads();
      const int sl = tt & RB, slp = (tt - 1) & RB;
      stage4k2(sh0, &p.h0r[((size_t)sl * B_ + bq * 8) * H_],
               sh1, &p.h1r[((size_t)slp * B_ + bq * 8) * H_], t);
      float acc[4];
      const float* xs = &p.strokes[(b * T_ + tt) * 3];
      float x0 = xs[0], x1 = xs[1], x2 = xs[2];
      #pragma unroll
      for (int g = 0; g < 4; ++g) {
        int cg = g * H_ + col;
        acc[g] = p.b1[cg] + x0 * p.W1[576 * C4_ + cg] + x1 * p.W1[577 * C4_ + cg]
                          + x2 * p.W1[578 * C4_ + cg];
      }
      __syncthreads();
      dot4gl(sh0 + bl * H_, p.PH1, H_ / 4, col, acc);
      dot4gl(sh1 + bl * H_, p.PR1, H_ / 4, col, acc);
      if (t == 0) waitflag(FP(p.wfl, tt, bq), 1);
      __syncthreads();
      stage512(sw, &p.wr[((size_t)sl * B_ + bq * 8) * N_], t);
      __syncthreads();
      dot4gl(sw + bl * N_, p.PW1w, N_ / 4, col, acc);
      float cn = sigf(acc[1]) * creg + sigf(acc[0]) * tanhf(acc[2]);
      float hn = sigf(acc[3]) * tanhf(cn);
      creg = cn;
      cstoref(&p.h1r[((size_t)sl * B_ + b) * H_ + col], hn);
      __syncthreads();
      if (t == 0) postflag(FP(p.h1f, tt, bq));
    }
  } else if (q < NB_L0 + NB_L1 + NB_L2) {            // ---- layer 2 ----
    const int qq = q - NB_L0 - NB_L1;
    const int bq = qq >> 3, colg = qq & 7;
    const int bl = t >> 6, cl = t & 63;
    const int b = bq * 8 + bl, col = colg * 64 + cl;
    float* sh1 = s_buf;           // h1(tt)
    float* sh2 = s_buf + 4096;    // h2(tt-1)
    float* sw  = s_buf + 8192;    // w(tt)
    float creg = 0.0f;
    for (int tt = 0; tt < T_; ++tt) {
      if (t == 0) {
        waitflag(FP(p.h1f, tt, bq), 8);
        waitflag(FP(p.wfl, tt, bq), 1);
        if (tt >= 1) waitflag(FP(p.h2f, tt - 1, bq), 8);
        if (tt >= 6) waitflag(FP(p.outf, tt - 6, bq), 1);
      }
      __syncthreads();
      const int sl = tt & RB, slp = (tt - 1) & RB;
      stage4k2(sh1, &p.h1r[((size_t)sl * B_ + bq * 8) * H_],
               sh2, &p.h2r[((size_t)slp * B_ + bq * 8) * H_], t);
      stage512(sw, &p.wr[((size_t)sl * B_ + bq * 8) * N_], t);
      float acc[4];
      const float* xs = &p.strokes[(b * T_ + tt) * 3];
      float x0 = xs[0], x1 = xs[1], x2 = xs[2];
      #pragma unroll
      for (int g = 0; g < 4; ++g) {
        int cg = g * H_ + col;
        acc[g] = p.b2[cg] + x0 * p.W2[576 * C4_ + cg] + x1 * p.W2[577 * C4_ + cg]
                          + x2 * p.W2[578 * C4_ + cg];
      }
      __syncthreads();
      dot4gl(sh1 + bl * H_, p.PH2, H_ / 4, col, acc);
      dot4gl(sw + bl * N_, p.PW2w, N_ / 4, col, acc);
      dot4gl(sh2 + bl * H_, p.PR2, H_ / 4, col, acc);
      float cn = sigf(acc[1]) * creg + sigf(acc[0]) * tanhf(acc[2]);
      float hn = sigf(acc[3]) * tanhf(cn);
      creg = cn;
      cstoref(&p.h2r[((size_t)sl * B_ + b) * H_ + col], hn);
      __syncthreads();
      if (t == 0) postflag(FP(p.h2f, tt, bq));
    }
  } else if (q < NB_L0 + NB_L1 + NB_L2 + NB_OUT) {   // ---- output head ----
    const int bq = q - NB_L0 - NB_L1 - NB_L2;
    const int bl = t >> 6, ol = t & 63;
    const int b = bq * 8 + bl;
    const int oo1 = ol;
    const bool v2 = (ol < O_ - 64);
    const int oo2 = v2 ? (ol + 64) : 0;
    float* sx0 = s_buf;
    float* sx1 = s_buf + 4096;
    float* sx2 = s_buf + 8192;
    for (int tt = 0; tt < T_; ++tt) {
      if (t == 0) {
        waitflag(FP(p.h0f, tt, bq), 8);
        waitflag(FP(p.h1f, tt, bq), 8);
        waitflag(FP(p.h2f, tt, bq), 8);
      }
      __syncthreads();
      const int sl = tt & RB;
      {  // 3-tile fused stage: one LLC round trip (12 back-to-back atomic loads)
        const double* a = (const double*)&p.h0r[((size_t)sl * B_ + bq * 8) * H_];
        const double* c = (const double*)&p.h1r[((size_t)sl * B_ + bq * 8) * H_];
        const double* e = (const double*)&p.h2r[((size_t)sl * B_ + bq * 8) * H_];
        double a0 = AL(a + t), a1 = AL(a + 512 + t), a2 = AL(a + 1024 + t), a3 = AL(a + 1536 + t);
        double c0 = AL(c + t), c1 = AL(c + 512 + t), c2 = AL(c + 1024 + t), c3 = AL(c + 1536 + t);
        double e0 = AL(e + t), e1 = AL(e + 512 + t), e2 = AL(e + 1024 + t), e3 = AL(e + 1536 + t);
        double* dA = (double*)sx0; dA[t] = a0; dA[512 + t] = a1; dA[1024 + t] = a2; dA[1536 + t] = a3;
        double* dC = (double*)sx1; dC[t] = c0; dC[512 + t] = c1; dC[1024 + t] = c2; dC[1536 + t] = c3;
        double* dE = (double*)sx2; dE[t] = e0; dE[512 + t] = e1; dE[1024 + t] = e2; dE[1536 + t] = e3;
      }
      __syncthreads();
      const float* X0 = sx0 + bl * H_;
      const float* X1 = sx1 + bl * H_;
      const float* X2 = sx2 + bl * H_;
      float a1v = p.bo[oo1];
      a1v += dot1l(X0, p.PWo + oo1, 128, O_);
      a1v += dot1l(X1, p.PWo + (size_t)128 * O_ + oo1, 128, O_);
      a1v += dot1l(X2, p.PWo + (size_t)256 * O_ + oo1, 128, O_);
      float a2v = p.bo[oo2];
      a2v += dot1l(X0, p.PWo + oo2, 128, O_);
      a2v += dot1l(X1, p.PWo + (size_t)128 * O_ + oo2, 128, O_);
      a2v += dot1l(X2, p.PWo + (size_t)256 * O_ + oo2, 128, O_);
      __builtin_nontemporal_store(a1v, &p.outp[(size_t)(b * T_ + tt) * O_ + oo1]);
      if (v2) __builtin_nontemporal_store(a2v, &p.outp[(size_t)(b * T_ + tt) * O_ + oo2]);
      __syncthreads();
      if (t == 0) postflag(FP(p.outf, tt, bq));
    }
  } else {                                           // ---- attention ----
    const int qa = q - NB_L0 - NB_L1 - NB_L2 - NB_OUT;
    const int lb = t >> 5, s = t & 31;
    const int ub = qa * 16 + lb;
    for (int z = t; z < 160; z += NTHR) ((float*)s_kap)[z] = 0.0f;
    __syncthreads();
    for (int tt = 0; tt < T_; ++tt) {
      if (t == 0) {
        waitflag(FP(p.h0f, tt, 2 * qa), 8);
        waitflag(FP(p.h0f, tt, 2 * qa + 1), 8);
      }
      __syncthreads();
      const int sl = tt & RB;
      {  // stage 16 rows (8192 floats) of h0(tt): 8 back-to-back loads
        const double* sA = (const double*)&p.h0r[((size_t)sl * B_ + qa * 16) * H_];
        double v[8];
        #pragma unroll
        for (int k = 0; k < 8; ++k) v[k] = AL(sA + k * 512 + t);
        double* d = (double*)s_buf;
        #pragma unroll
        for (int k = 0; k < 8; ++k) d[k * 512 + t] = v[k];
      }
      __syncthreads();
      if (s < 30) {
        float a = p.bd[s] + dot1l(s_buf + lb * H_, p.PWd + s, 128, 30);
        float y = expf(a);
        s_y[lb][s] = y;
        if (s >= 20) {
          float k2 = s_kap[lb][s - 20] + y;
          s_kap[lb][s - 20] = k2;
          s_k2[lb][s - 20] = k2;
        }
      }
      __syncthreads();
      // numpy-fp32 underflow-exact wfull (validated R3/R6: absmax 0.0156)
      for (int u = s; u < U_ + 1; u += 32) {
        double wf = 0.0;
        #pragma unroll
        for (int k = 0; k < KMIX; ++k) {
          float d32 = s_k2[lb][k] - (float)(u + 1);
          float sq  = d32 * d32;
          float m   = -(s_y[lb][10 + k] * sq);
          double e  = exp((double)m);
          double e32 = (e < 0x1p-126) ? 0.0 : (double)(float)e;
          wf += f32q((double)s_y[lb][k] * e32);
        }
        s_wf[lb][u] = wf;
      }
      __syncthreads();
      if (s == 0) {
        int am = 0; double bv = s_wf[lb][0];
        for (int u = 1; u < U_ + 1; ++u) {
          double v = s_wf[lb][u];
          if (v > bv) { bv = v; am = u; }
        }
        __builtin_nontemporal_store((float)am, &p.attp[ub * T_ + tt]);
      }
      for (int n = s; n < N_; n += 32) {
        float a2 = 0.f;
        for (int u = 0; u < U_; ++u)
          a2 = fmaf((float)s_wf[lb][u], p.transcr[(size_t)(ub * U_ + u) * N_ + n], a2);
        cstoref(&p.wr[((size_t)sl * B_ + ub) * N_ + n], a2);
      }
      __syncthreads();
      if (t == 0) {
        postflag(FP(p.wfl, tt, 2 * qa));
        postflag(FP(p.wfl, tt, 2 * qa + 1));
      }
    }
  }
}

extern "C" void kernel_launch(void* const* d_in, const int* in_sizes, int n_in,
                              void* d_out, int out_size, void* d_ws, size_t ws_size,
                              hipStream_t stream) {
  (void)in_sizes; (void)n_in; (void)out_size; (void)ws_size;
  const float* strokes = (const float*)d_in[0];
  const float* transcr = (const float*)d_in[1];
  const float* W0 = (const float*)d_in[2];
  const float* R0 = (const float*)d_in[3];
  const float* b0 = (const float*)d_in[4];
  const float* Wd = (const float*)d_in[5];
  const float* bd = (const float*)d_in[6];
  const float* W1 = (const float*)d_in[7];
  const float* R1 = (const float*)d_in[8];
  const float* b1 = (const float*)d_in[9];
  const float* W2 = (const float*)d_in[10];
  const float* R2 = (const float*)d_in[11];
  const float* b2 = (const float*)d_in[12];
  const float* Wo = (const float*)d_in[13];
  const float* bo = (const float*)d_in[14];

  float* ws = (float*)d_ws;
  size_t off = 0;
  float* h0r = ws + off; off += (size_t)RING * B_ * H_;
  float* h1r = ws + off; off += (size_t)RING * B_ * H_;
  float* h2r = ws + off; off += (size_t)RING * B_ * H_;
  float* wr  = ws + off; off += (size_t)RING * B_ * N_;
  const size_t FLAGN = (size_t)T_ * 8 * FS;
  int* h0f  = (int*)(ws + off); off += FLAGN;
  int* h1f  = (int*)(ws + off); off += FLAGN;
  int* h2f  = (int*)(ws + off); off += FLAGN;
  int* wfl  = (int*)(ws + off); off += FLAGN;
  int* outf = (int*)(ws + off); off += FLAGN;
  size_t stateFloats = off;
  float* PR0  = ws + off; off += (size_t)512 * 2048;
  float* PW0w = ws + off; off += (size_t)64 * 2048;
  float* PH1  = ws + off; off += (size_t)512 * 2048;
  float* PR1  = ws + off; off += (size_t)512 * 2048;
  float* PW1w = ws + off; off += (size_t)64 * 2048;
  float* PH2  = ws + off; off += (size_t)512 * 2048;
  float* PR2  = ws + off; off += (size_t)512 * 2048;
  float* PW2w = ws + off; off += (size_t)64 * 2048;
  float* PWo  = ws + off; off += (size_t)1536 * 121;
  float* PWd  = ws + off; off += (size_t)512 * 30;

  // zero rings + flags (ws is poisoned 0xAA before every call)
  (void)hipMemsetAsync(d_ws, 0, stateFloats * sizeof(float), stream);

  auto packl = [&](const float* src, float* dst, int K, int C, int ld) {
    int n = K * C;
    pack_k<<<dim3((n + 255) / 256), dim3(256), 0, stream>>>(src, dst, K, C, ld);
  };
  packl(R0, PR0, 512, 2048, 2048);
  packl(W0 + 3 * 2048, PW0w, 64, 2048, 2048);
  packl(W1, PH1, 512, 2048, 2048);
  packl(R1, PR1, 512, 2048, 2048);
  packl(W1 + 512 * 2048, PW1w, 64, 2048, 2048);
  packl(W2, PH2, 512, 2048, 2048);
  packl(R2, PR2, 512, 2048, 2048);
  packl(W2 + 512 * 2048, PW2w, 64, 2048, 2048);
  packl(Wo, PWo, 1536, 121, 121);
  packl(Wd, PWd, 512, 30, 30);

  Params p;
  p.strokes = strokes; p.transcr = transcr;
  p.W0 = W0; p.b0 = b0; p.bd = bd;
  p.W1 = W1; p.b1 = b1; p.W2 = W2; p.b2 = b2; p.bo = bo;
  p.PR0 = (const float4*)PR0; p.PW0w = (const float4*)PW0w;
  p.PH1 = (const float4*)PH1; p.PR1 = (const float4*)PR1; p.PW1w = (const float4*)PW1w;
  p.PH2 = (const float4*)PH2; p.PR2 = (const float4*)PR2; p.PW2w = (const float4*)PW2w;
  p.PWo = (const float4*)PWo; p.PWd = (const float4*)PWd;
  p.h0r = h0r; p.h1r = h1r; p.h2r = h2r; p.wr = wr;
  p.h0f = h0f; p.h1f = h1f; p.h2f = h2f; p.wfl = wfl; p.outf = outf;
  p.outp = (float*)d_out;
  p.attp = (float*)d_out + (size_t)B_ * T_ * O_;

  void* args[] = { (void*)&p };
  (void)hipLaunchCooperativeKernel((const void*)net_kernel, dim3(NBLK), dim3(NTHR),
                                   args, 0, stream);
}